// Round 2
// baseline (489.458 us; speedup 1.0000x reference)
//
#include <hip/hip_runtime.h>

// ---------------------------------------------------------------------------
// loss = 0.5*(ce(hard) + relu(ce(mean)-R)),  logits = (inputs @ features^T)/TEMP
// B=256 rows, D=256, features rows = 131072 (first 65536 = "mean" half).
//
// R6 redesign: barrier-free streaming GEMM.
//  - F (134 MB) is streamed global->VGPR->MFMA directly as the A-operand of
//    mfma_f32_32x32x16_f16 (K-contiguous rows match the 8-contiguous-k lane
//    fragment). No LDS staging of F, no double-buffer, NO barriers in the
//    main loop (the old per-tile __syncthreads emitted vmcnt(0) drains that
//    defeated the prefetch pipeline entirely).
//  - inputs (small, 256x256) sit in LDS as f16, XOR-swizzled (ck ^= row&7),
//    written once in the prologue; read as B-fragments (batch = lane&31).
//  - 512 blocks x 512 threads (8 waves): block = (batch-half h, 512 features).
//    64 KB LDS -> 2 blocks/CU, 16 waves/CU. Wave w covers features
//    fblk*512 + w*64 (two 32-feature passes), batch h*128..h*128+127.
//  - acc: 4 x f32x16 (256 batch cols x 32 features per pass). exp(logit-20)
//    folded per pass; per-feature row mapping is irrelevant (summed), only
//    col=lane&31 (HW-verified) is consumed.
//  - partial stays [256][256] (block fblk covers features [fblk*512,+512)),
//    mean half = fblk<128, batch rows disjoint by h -> finalize unchanged.
// Model: HBM leg 21 us/CU, LDS reads 10 us, MFMA 8 us, all overlapped.
// ---------------------------------------------------------------------------

typedef _Float16 half8 __attribute__((ext_vector_type(8)));
typedef float float4v __attribute__((ext_vector_type(4)));
typedef float float2v __attribute__((ext_vector_type(2)));
typedef float float16v __attribute__((ext_vector_type(16)));

#define BROWS 256       // batch rows (M)
#define DDIM 256        // reduction (K)
#define NCOLS 131072    // total feature rows (2N)
#define NHALF 65536
#define NBLOCKS 256     // partial[] column count (finalize contract)
#define GBLOCKS 512     // gemm grid: 256 feature-superblocks x 2 batch halves
#define THREADS 512     // 8 waves
#define ROWB 512        // bytes per LDS row (256 f16)

__global__ __launch_bounds__(THREADS, 4)
void gemm_lse_kernel(const float* __restrict__ A,   // [256][256]
                     const float* __restrict__ F,   // [131072][256]
                     float* __restrict__ partial)   // [256][NBLOCKS]
{
    __shared__ __align__(16) char lds[128 * ROWB];  // 64 KB: inputs half, f16

    const int tid  = threadIdx.x;
    const int lane = tid & 63;
    const int w    = tid >> 6;        // wave 0..7
    const int m    = lane & 31;       // MFMA row/col within 32
    const int hi   = lane >> 5;       // k-half 0/1
    const int h    = blockIdx.x & 1;  // batch half
    const int fblk = blockIdx.x >> 1; // feature superblock 0..255 (512 features)

    // ---- prologue: stage inputs[h*128 .. +128) into LDS as f16, swizzled ----
    // thread t: local row r = t>>2, k-quarter q = t&3 (64 f32 = 8 chunks of 16B)
    {
        const int r = tid >> 2;
        const int q = tid & 3;
        const float* ap = A + (size_t)(h * 128 + r) * DDIM + q * 64;
        float4v x[16];
#pragma unroll
        for (int i = 0; i < 16; i++) x[i] = *(const float4v*)(ap + i * 4);
#pragma unroll
        for (int cc = 0; cc < 8; cc++) {
            const float4v a0 = x[cc * 2], a1 = x[cc * 2 + 1];
            half8 hh;
            hh[0] = (_Float16)a0[0]; hh[1] = (_Float16)a0[1];
            hh[2] = (_Float16)a0[2]; hh[3] = (_Float16)a0[3];
            hh[4] = (_Float16)a1[0]; hh[5] = (_Float16)a1[1];
            hh[6] = (_Float16)a1[2]; hh[7] = (_Float16)a1[3];
            const int ck = q * 8 + cc;                     // 16B chunk 0..31
            *(half8*)(lds + r * ROWB + ((ck ^ (r & 7)) << 4)) = hh;
        }
    }
    __syncthreads();   // the ONLY barrier before the reduction epilogue

    float rowsum[4] = {0.f, 0.f, 0.f, 0.f};
    const int fbase = fblk * 512 + w * 64;

#pragma unroll
    for (int p = 0; p < 2; p++) {
        // this pass: features f0..f0+31 (A-operand), batch h*128..+128 (B-op)
        const int f0 = fbase + p * 32;
        const float* fp = F + (size_t)(f0 + m) * DDIM + hi * 8;

        float16v acc[4];
#pragma unroll
        for (int nb = 0; nb < 4; nb++)
#pragma unroll
            for (int i = 0; i < 16; i++) acc[nb][i] = 0.f;

        // K loop: 16 steps of K=16; F-fragment loaded global->reg, distance-1
        float4v nx0 = *(const float4v*)(fp);
        float4v nx1 = *(const float4v*)(fp + 4);
#pragma unroll
        for (int kb = 0; kb < 16; kb++) {
            const float4v cx0 = nx0, cx1 = nx1;
            if (kb < 15) {
                nx0 = *(const float4v*)(fp + (kb + 1) * 16);
                nx1 = *(const float4v*)(fp + (kb + 1) * 16 + 4);
            }
            half8 af;   // A-frag: F[f0 + m][kb*16 + hi*8 + j]
            af[0] = (_Float16)cx0[0]; af[1] = (_Float16)cx0[1];
            af[2] = (_Float16)cx0[2]; af[3] = (_Float16)cx0[3];
            af[4] = (_Float16)cx1[0]; af[5] = (_Float16)cx1[1];
            af[6] = (_Float16)cx1[2]; af[7] = (_Float16)cx1[3];

            half8 bf[4];
#pragma unroll
            for (int nb = 0; nb < 4; nb++) {
                // B-frag: inputs[h*128 + nb*32 + m][kb*16 + hi*8 + j]
                const int bl = nb * 32 + m;          // local batch row
                const int ck = kb * 2 + hi;          // 16B chunk
                bf[nb] = *(const half8*)(lds + bl * ROWB + ((ck ^ (bl & 7)) << 4));
            }
#pragma unroll
            for (int nb = 0; nb < 4; nb++)
                acc[nb] = __builtin_amdgcn_mfma_f32_32x32x16_f16(
                    af, bf[nb], acc[nb], 0, 0, 0);
        }

        // epilogue: exp(logit - 20); only col identity (batch = lane&31) used
#pragma unroll
        for (int nb = 0; nb < 4; nb++)
#pragma unroll
            for (int r = 0; r < 16; r++)
                rowsum[nb] += __expf(fmaf(acc[nb][r], 20.f, -20.f));
    }

    // fold k-halves: lanes l and l^32 hold complementary feature subsets
#pragma unroll
    for (int nb = 0; nb < 4; nb++)
        rowsum[nb] += __shfl_xor(rowsum[nb], 32);

    // block reduction over the 8 waves (all same batch half)
    __syncthreads();                 // everyone done reading inputs LDS
    float* sums = (float*)lds;       // reuse LDS
    if (tid < 128) sums[tid] = 0.f;
    __syncthreads();
    if (hi == 0) {
#pragma unroll
        for (int nb = 0; nb < 4; nb++)
            atomicAdd(&sums[nb * 32 + m], rowsum[nb]);
    }
    __syncthreads();
    if (tid < 128)
        partial[(size_t)(h * 128 + tid) * NBLOCKS + fblk] = sums[tid];
}

// One block per batch row, 64 threads: per-row CE terms -> ce[b] = {cem, ceh}.
__global__ __launch_bounds__(64)
void finalize_rows(const float* __restrict__ partial,  // [256][NBLOCKS]
                   const float* __restrict__ A,
                   const float* __restrict__ F,
                   const int* __restrict__ targets,
                   float2v* __restrict__ ce)           // [256]
{
    const int b = blockIdx.x;
    const int l = threadIdx.x;   // 0..63

    // partials row: 256 floats; lane l sums one float4.
    // p4[0..31] = mean half (blocks 0..127), p4[32..63] = hard half.
    const float4v* p4 = (const float4v*)(partial + b * NBLOCKS);
    const float4v x = p4[l];
    const float s = x[0] + x[1] + x[2] + x[3];
    float smv = (l < 32) ? s : 0.f;
    float shv = (l < 32) ? 0.f : s;

    // target-logit dots: lane l covers D-elements [4l, 4l+4)
    const int t = targets[b];
    const float4v a  = *(const float4v*)(A + b * DDIM + l * 4);
    const float4v xm = *(const float4v*)(F + (size_t)t * DDIM + l * 4);
    const float4v xh = *(const float4v*)(F + (size_t)(t + NHALF) * DDIM + l * 4);
    float dm = a[0] * xm[0] + a[1] * xm[1] + a[2] * xm[2] + a[3] * xm[3];
    float dh = a[0] * xh[0] + a[1] * xh[1] + a[2] * xh[2] + a[3] * xh[3];

#pragma unroll
    for (int msk = 1; msk < 64; msk <<= 1) {
        smv += __shfl_xor(smv, msk);
        shv += __shfl_xor(shv, msk);
        dm  += __shfl_xor(dm, msk);
        dh  += __shfl_xor(dh, msk);
    }
    if (l == 0) {
        // CE = LSE - target_logit ; LSE = 20 + ln(sum of exp(logit-20))
        float2v r;
        r[0] = 20.f + __logf(smv) - dm * 20.f;
        r[1] = 20.f + __logf(shv) - dh * 20.f;
        ce[b] = r;
    }
}

__global__ __launch_bounds__(256)
void finalize_loss(const float2v* __restrict__ ce,  // [256]
                   float* __restrict__ out)
{
    const float2v c = ce[threadIdx.x];
    float cem = c[0], ceh = c[1];
#pragma unroll
    for (int msk = 1; msk < 64; msk <<= 1) {
        cem += __shfl_xor(cem, msk);
        ceh += __shfl_xor(ceh, msk);
    }
    __shared__ float sb[8];
    const int wv = threadIdx.x >> 6;
    if ((threadIdx.x & 63) == 0) { sb[wv] = cem; sb[4 + wv] = ceh; }
    __syncthreads();
    if (threadIdx.x == 0) {
        const float cm = (sb[0] + sb[1] + sb[2] + sb[3]) * (1.f / 256.f);
        const float ch = (sb[4] + sb[5] + sb[6] + sb[7]) * (1.f / 256.f);
        const float rl = cm - 0.2f;
        out[0] = 0.5f * (ch + (rl > 0.f ? rl : 0.f));
    }
}

extern "C" void kernel_launch(void* const* d_in, const int* in_sizes, int n_in,
                              void* d_out, int out_size, void* d_ws, size_t ws_size,
                              hipStream_t stream) {
    const float* inputs   = (const float*)d_in[0];   // [256,256] f32
    const int*   targets  = (const int*)d_in[1];     // [256] int
    const float* features = (const float*)d_in[2];   // [131072,256] f32
    float* out = (float*)d_out;
    float* partial = (float*)d_ws;                   // 256*NBLOCKS floats = 256 KB
    float2v* ce = (float2v*)((char*)d_ws + BROWS * NBLOCKS * sizeof(float)); // 2 KB

    gemm_lse_kernel<<<GBLOCKS, THREADS, 0, stream>>>(inputs, features, partial);
    finalize_rows<<<BROWS, 64, 0, stream>>>(partial, inputs, features, targets, ce);
    finalize_loss<<<1, 256, 0, stream>>>(ce, out);
}

// Round 3
// 260.176 us; speedup vs baseline: 1.8813x; 1.8813x over previous
//
#include <hip/hip_runtime.h>

// ---------------------------------------------------------------------------
// loss = 0.5*(ce(hard) + relu(ce(mean)-R)),  logits = (inputs @ features^T)/TEMP
// B=256 rows, D=256, features rows = 131072 (first 65536 = "mean" half).
//
// R7: fix R6's two measured diseases (rocprof: WRITE_SIZE=666MB spill traffic
// from the 128-reg launch_bounds cap; FETCH_SIZE=534MB = 4x ideal, 2x of it
// from the batch-half split reading F twice).
//  - __launch_bounds__(512, 2): 256-reg budget -> no spill (demand ~150;
//    acc 4 x f32x16 lives in AGPRs). LDS caps occupancy at 1 block/CU anyway.
//  - One block = 512 features x FULL 256-row batch. inputs (256x256) sits
//    whole in 128 KB LDS f16, XOR-swizzled, staged once. Grid = 256 blocks
//    (1/CU). Wave w: feature-set fs=w&3, batch-half bh=w>>2; 4 passes of
//    32 features x 128 batch. Both bh-waves stream the same F rows ->
//    second reader hits L1/L2 -> F fetched from HBM exactly once (134 MB).
//  - F streams global->VGPR->MFMA (A-operand of mfma_f32_32x32x16_f16,
//    K-contiguous). NO barriers in the main loop. Distance-2 rolling
//    prefetch (static reg slots): 8 waves x 2 wave-loads x 2KB = 32KB in
//    flight/CU > ~22KB BW*latency product.
//  - exp(logit-20) folded per pass (logits<=20, unit-norm rows); only the
//    HW-verified C/D col=lane&31 identity is consumed (features summed).
// Model: HBM leg 134MB ~21-39us; LDS reads ~10-16us; MFMA ~7us; VALU ~5us,
// all overlapped, no barriers. Predict gemm 30-45us, WRITE_SIZE < 2MB.
// ---------------------------------------------------------------------------

typedef _Float16 half8 __attribute__((ext_vector_type(8)));
typedef float float4v __attribute__((ext_vector_type(4)));
typedef float float2v __attribute__((ext_vector_type(2)));
typedef float float16v __attribute__((ext_vector_type(16)));

#define BROWS 256       // batch rows (M)
#define DDIM 256        // reduction (K)
#define NCOLS 131072    // total feature rows (2N)
#define NHALF 65536
#define NBLOCKS 256     // partial[] column count (finalize contract)
#define THREADS 512     // 8 waves
#define ROWB 512        // bytes per LDS row (256 f16)

__global__ __launch_bounds__(THREADS, 2)
void gemm_lse_kernel(const float* __restrict__ A,   // [256][256]
                     const float* __restrict__ F,   // [131072][256]
                     float* __restrict__ partial)   // [256][NBLOCKS]
{
    __shared__ __align__(16) char lds[256 * ROWB];  // 128 KB: all inputs, f16

    const int tid  = threadIdx.x;
    const int lane = tid & 63;
    const int w    = tid >> 6;        // wave 0..7
    const int m    = lane & 31;       // MFMA row/col within 32
    const int hi   = lane >> 5;       // k-half 0/1
    const int fs   = w & 3;           // feature subset within pass
    const int bh   = w >> 2;          // batch half 0/1
    const int fblk = blockIdx.x;      // feature superblock (512 features)

    // ---- prologue: stage ALL 256 input rows into LDS as f16, swizzled ----
    // thread t: row r = t>>1, k-half q = t&1 (128 f32 = 16 chunks of 16B)
    {
        const int r = tid >> 1;
        const int q = tid & 1;
        const float* ap = A + (size_t)r * DDIM + q * 128;
#pragma unroll
        for (int cc = 0; cc < 16; cc++) {
            const float4v a0 = *(const float4v*)(ap + cc * 8);
            const float4v a1 = *(const float4v*)(ap + cc * 8 + 4);
            half8 hh;
            hh[0] = (_Float16)a0[0]; hh[1] = (_Float16)a0[1];
            hh[2] = (_Float16)a0[2]; hh[3] = (_Float16)a0[3];
            hh[4] = (_Float16)a1[0]; hh[5] = (_Float16)a1[1];
            hh[6] = (_Float16)a1[2]; hh[7] = (_Float16)a1[3];
            const int ck = q * 16 + cc;                    // 16B chunk 0..31
            *(half8*)(lds + r * ROWB + ((ck ^ (r & 7)) << 4)) = hh;
        }
    }
    __syncthreads();   // the ONLY barrier before the reduction epilogue

    float rowsum[4] = {0.f, 0.f, 0.f, 0.f};

#pragma unroll 1
    for (int p = 0; p < 4; p++) {
        // this pass: features f0..f0+31 (A-op), batch bh*128..+128 (B-op)
        const int f0 = fblk * 512 + p * 128 + fs * 32 + m;
        const float* fp = F + (size_t)f0 * DDIM + hi * 8;

        float16v acc[4];
#pragma unroll
        for (int nb = 0; nb < 4; nb++)
#pragma unroll
            for (int i = 0; i < 16; i++) acc[nb][i] = 0.f;

        // K loop: 16 steps of K=16; rolling distance-2 prefetch, static slots
        float4v pa0 = *(const float4v*)(fp);
        float4v pb0 = *(const float4v*)(fp + 4);
        float4v pa1 = *(const float4v*)(fp + 16);
        float4v pb1 = *(const float4v*)(fp + 20);

#pragma unroll
        for (int kb = 0; kb < 16; kb += 2) {
            // ---- step kb (slot 0) ----
            {
                const float4v c0 = pa0, c1 = pb0;
                if (kb + 2 < 16) {
                    pa0 = *(const float4v*)(fp + (kb + 2) * 16);
                    pb0 = *(const float4v*)(fp + (kb + 2) * 16 + 4);
                }
                half8 af;   // A-frag: F[f0][kb*16 + hi*8 + j]
                af[0] = (_Float16)c0[0]; af[1] = (_Float16)c0[1];
                af[2] = (_Float16)c0[2]; af[3] = (_Float16)c0[3];
                af[4] = (_Float16)c1[0]; af[5] = (_Float16)c1[1];
                af[6] = (_Float16)c1[2]; af[7] = (_Float16)c1[3];
#pragma unroll
                for (int nb = 0; nb < 4; nb++) {
                    const int bl = bh * 128 + nb * 32 + m;   // batch row
                    const int ck = kb * 2 + hi;              // 16B chunk
                    const half8 bf = *(const half8*)(lds + bl * ROWB + ((ck ^ (bl & 7)) << 4));
                    acc[nb] = __builtin_amdgcn_mfma_f32_32x32x16_f16(af, bf, acc[nb], 0, 0, 0);
                }
            }
            // ---- step kb+1 (slot 1) ----
            {
                const float4v c0 = pa1, c1 = pb1;
                if (kb + 3 < 16) {
                    pa1 = *(const float4v*)(fp + (kb + 3) * 16);
                    pb1 = *(const float4v*)(fp + (kb + 3) * 16 + 4);
                }
                half8 af;
                af[0] = (_Float16)c0[0]; af[1] = (_Float16)c0[1];
                af[2] = (_Float16)c0[2]; af[3] = (_Float16)c0[3];
                af[4] = (_Float16)c1[0]; af[5] = (_Float16)c1[1];
                af[6] = (_Float16)c1[2]; af[7] = (_Float16)c1[3];
#pragma unroll
                for (int nb = 0; nb < 4; nb++) {
                    const int bl = bh * 128 + nb * 32 + m;
                    const int ck = (kb + 1) * 2 + hi;
                    const half8 bf = *(const half8*)(lds + bl * ROWB + ((ck ^ (bl & 7)) << 4));
                    acc[nb] = __builtin_amdgcn_mfma_f32_32x32x16_f16(af, bf, acc[nb], 0, 0, 0);
                }
            }
        }

        // epilogue: exp(logit - 20); only col identity (batch = lane&31) used
#pragma unroll
        for (int nb = 0; nb < 4; nb++)
#pragma unroll
            for (int r = 0; r < 16; r++)
                rowsum[nb] += __expf(fmaf(acc[nb][r], 20.f, -20.f));
    }

    // fold k-halves: lanes l and l^32 hold complementary feature subsets
#pragma unroll
    for (int nb = 0; nb < 4; nb++)
        rowsum[nb] += __shfl_xor(rowsum[nb], 32);

    // block reduction: 4 fs-waves per batch row set; LDS f32 atomics
    __syncthreads();                 // everyone done reading inputs LDS
    float* sums = (float*)lds;       // reuse LDS: sums[256] by batch row
    if (tid < 256) sums[tid] = 0.f;
    __syncthreads();
    if (hi == 0) {
#pragma unroll
        for (int nb = 0; nb < 4; nb++)
            atomicAdd(&sums[bh * 128 + nb * 32 + m], rowsum[nb]);
    }
    __syncthreads();
    if (tid < 256)
        partial[(size_t)tid * NBLOCKS + fblk] = sums[tid];
}

// One block per batch row, 64 threads: per-row CE terms -> ce[b] = {cem, ceh}.
__global__ __launch_bounds__(64)
void finalize_rows(const float* __restrict__ partial,  // [256][NBLOCKS]
                   const float* __restrict__ A,
                   const float* __restrict__ F,
                   const int* __restrict__ targets,
                   float2v* __restrict__ ce)           // [256]
{
    const int b = blockIdx.x;
    const int l = threadIdx.x;   // 0..63

    // partials row: 256 floats; lane l sums one float4.
    // p4[0..31] = mean half (blocks 0..127), p4[32..63] = hard half.
    const float4v* p4 = (const float4v*)(partial + b * NBLOCKS);
    const float4v x = p4[l];
    const float s = x[0] + x[1] + x[2] + x[3];
    float smv = (l < 32) ? s : 0.f;
    float shv = (l < 32) ? 0.f : s;

    // target-logit dots: lane l covers D-elements [4l, 4l+4)
    const int t = targets[b];
    const float4v a  = *(const float4v*)(A + b * DDIM + l * 4);
    const float4v xm = *(const float4v*)(F + (size_t)t * DDIM + l * 4);
    const float4v xh = *(const float4v*)(F + (size_t)(t + NHALF) * DDIM + l * 4);
    float dm = a[0] * xm[0] + a[1] * xm[1] + a[2] * xm[2] + a[3] * xm[3];
    float dh = a[0] * xh[0] + a[1] * xh[1] + a[2] * xh[2] + a[3] * xh[3];

#pragma unroll
    for (int msk = 1; msk < 64; msk <<= 1) {
        smv += __shfl_xor(smv, msk);
        shv += __shfl_xor(shv, msk);
        dm  += __shfl_xor(dm, msk);
        dh  += __shfl_xor(dh, msk);
    }
    if (l == 0) {
        // CE = LSE - target_logit ; LSE = 20 + ln(sum of exp(logit-20))
        float2v r;
        r[0] = 20.f + __logf(smv) - dm * 20.f;
        r[1] = 20.f + __logf(shv) - dh * 20.f;
        ce[b] = r;
    }
}

__global__ __launch_bounds__(256)
void finalize_loss(const float2v* __restrict__ ce,  // [256]
                   float* __restrict__ out)
{
    const float2v c = ce[threadIdx.x];
    float cem = c[0], ceh = c[1];
#pragma unroll
    for (int msk = 1; msk < 64; msk <<= 1) {
        cem += __shfl_xor(cem, msk);
        ceh += __shfl_xor(ceh, msk);
    }
    __shared__ float sb[8];
    const int wv = threadIdx.x >> 6;
    if ((threadIdx.x & 63) == 0) { sb[wv] = cem; sb[4 + wv] = ceh; }
    __syncthreads();
    if (threadIdx.x == 0) {
        const float cm = (sb[0] + sb[1] + sb[2] + sb[3]) * (1.f / 256.f);
        const float ch = (sb[4] + sb[5] + sb[6] + sb[7]) * (1.f / 256.f);
        const float rl = cm - 0.2f;
        out[0] = 0.5f * (ch + (rl > 0.f ? rl : 0.f));
    }
}

extern "C" void kernel_launch(void* const* d_in, const int* in_sizes, int n_in,
                              void* d_out, int out_size, void* d_ws, size_t ws_size,
                              hipStream_t stream) {
    const float* inputs   = (const float*)d_in[0];   // [256,256] f32
    const int*   targets  = (const int*)d_in[1];     // [256] int
    const float* features = (const float*)d_in[2];   // [131072,256] f32
    float* out = (float*)d_out;
    float* partial = (float*)d_ws;                   // 256*NBLOCKS floats = 256 KB
    float2v* ce = (float2v*)((char*)d_ws + BROWS * NBLOCKS * sizeof(float)); // 2 KB

    gemm_lse_kernel<<<NBLOCKS, THREADS, 0, stream>>>(inputs, features, partial);
    finalize_rows<<<BROWS, 64, 0, stream>>>(partial, inputs, features, targets, ce);
    finalize_loss<<<1, 256, 0, stream>>>(ce, out);
}